// Round 1
// 284.501 us; speedup vs baseline: 1.0121x; 1.0121x over previous
//
#include <hip/hip_runtime.h>
#include <hip/hip_fp16.h>

#define FIN 128
#define FH 50
#define HSTRIDE 64
#define MAXNB 1024        // supports n <= 131072 with 128-node buckets
#define BSHIFT 7
#define BSIZE 128
#define CAP 3072          // slab capacity per bucket (mean 2046, ~22 sigma margin)
#define PCHUNK 4096       // edges per partition workgroup
#define SRCMASK 0x01FFFFFFu

// -------- CSR build: slab-based two-level counting sort --------

// partition edges into per-bucket slabs: word = (dlocal<<25)|src.
// gcursor[b] (init 0) doubles as reservation cursor and final bucket count.
__global__ __launch_bounds__(256) void partition_kernel(const int* __restrict__ src,
                                                        const int* __restrict__ dst,
                                                        int* __restrict__ gcursor,
                                                        unsigned int* __restrict__ packed,
                                                        int E, int NB) {
    __shared__ int hist[MAXNB];   // phase1: counts; phase3: local cursor
    __shared__ int wbase[MAXNB];
    int t = threadIdx.x;
    int base = blockIdx.x * PCHUNK;
    for (int i = t; i < NB; i += 256) hist[i] = 0;
    __syncthreads();
#pragma unroll 4
    for (int i = 0; i < PCHUNK / 256; i++) {
        int e = base + t + i * 256;
        if (e < E) atomicAdd(&hist[dst[e] >> BSHIFT], 1);
    }
    __syncthreads();
    for (int i = t; i < NB; i += 256) {
        int c = hist[i];
        wbase[i] = c ? atomicAdd(&gcursor[i], c) : 0;
        hist[i] = 0;   // becomes local cursor
    }
    __syncthreads();
#pragma unroll 4
    for (int i = 0; i < PCHUNK / 256; i++) {
        int e = base + t + i * 256;
        if (e < E) {
            unsigned int s = (unsigned int)src[e];
            int d = dst[e];
            int b = d >> BSHIFT;
            int off = atomicAdd(&hist[b], 1);
            packed[(size_t)b * CAP + wbase[b] + off] =
                ((unsigned int)(d & (BSIZE - 1)) << 25) | s;
        }
    }
}

// one WG per bucket: local degree hist -> scan -> rbeg/rend/dinv -> csr fill
__global__ __launch_bounds__(256) void bucket_build_kernel(const unsigned int* __restrict__ packed,
                                                           const int* __restrict__ gcursor,
                                                           int* __restrict__ rbeg,
                                                           int* __restrict__ rend,
                                                           float* __restrict__ dinv,
                                                           int* __restrict__ csr, int n) {
    __shared__ int degl[BSIZE];
    __shared__ int excl[BSIZE];
    __shared__ int lcur[BSIZE];
    int b = blockIdx.x;
    int t = threadIdx.x;
    int nbeg = b << BSHIFT;
    int sbase = b * CAP;
    int cnt = gcursor[b];
    if (t < BSIZE) degl[t] = 0;
    __syncthreads();
    for (int e = t; e < cnt; e += 256)
        atomicAdd(&degl[packed[sbase + e] >> 25], 1);
    __syncthreads();
    int v = (t < BSIZE) ? degl[t] : 0;
    if (t < BSIZE) excl[t] = v;
    __syncthreads();
    for (int off = 1; off < BSIZE; off <<= 1) {
        int add = (t >= off && t < BSIZE) ? excl[t - off] : 0;
        __syncthreads();
        if (t < BSIZE) excl[t] += add;
        __syncthreads();
    }
    if (t < BSIZE) {
        int ex = excl[t] - v;
        int node = nbeg + t;
        if (node < n) {
            rbeg[node] = sbase + ex;
            rend[node] = sbase + ex + v;
            dinv[node] = rsqrtf((float)v + 1.0f);  // +1 = self-loop
        }
        lcur[t] = ex;
    }
    __syncthreads();
    for (int e = t; e < cnt; e += 256) {
        unsigned int w = packed[sbase + e];
        int off = atomicAdd(&lcur[w >> 25], 1);
        csr[sbase + off] = (int)(w & SRCMASK);
    }
}

// -------- dense compute --------

// hs1[row] = fp16((x[row] @ W1) * dinv[row]), stride 64, pad zeroed.
// K split across thread pairs (kh = tid&1); partials combined via shfl_xor.
// W1 staged c-major in LDS: Ws[c][136] floats, kh=1 half at float-offset 68
// (68 mod 32 = 4 -> the pair's two ds_read_b128 broadcast addresses hit
// disjoint bank groups {b..b+3} vs {b+4..b+7}: conflict-free). One b128
// read feeds 4 FMAs vs the old 1 b32 per FMA (was LDS-issue bound: 10M
// ds_read_b32 + 1e7 conflict cycles = ~60us).
#define W1S 136            // c-stride in floats (= 34 float4)
__global__ __launch_bounds__(256) void gemm1_kernel(
    const float* __restrict__ x, const float* __restrict__ W,
    const float* __restrict__ dinv, __half* __restrict__ hs1,
    __half* __restrict__ hs2, int n) {
    __shared__ __align__(16) float Ws[FH * W1S];   // 27.2 KB -> 5 blocks/CU
    int t = threadIdx.x;
    for (int i = t; i < FIN * FH; i += 256) {
        int k = i / FH;
        int c = i - k * FH;
        Ws[c * W1S + k + ((k >> 6) << 2)] = W[i];  // k>=64 shifted +4 floats
    }
    if (blockIdx.x == 0) {
        if (t < HSTRIDE)           hs1[((size_t)n << 6) + t] = __float2half(0.f);
        else if (t < 2 * HSTRIDE)  hs2[((size_t)n << 6) + (t - HSTRIDE)] = __float2half(0.f);
    }
    __syncthreads();
    int row = blockIdx.x * 128 + (t >> 1);
    int kh = t & 1;
    if (row >= n) return;   // pairs (and waves) cross the boundary together
    float a[FH];
#pragma unroll
    for (int c = 0; c < FH; c++) a[c] = 0.f;
    const float4* xr = (const float4*)(x + (size_t)row * FIN + kh * 64);
    const float4* W4 = (const float4*)Ws;
    int wbase = kh * 17;                     // float4 units (= kh*68 floats)
    for (int k4 = 0; k4 < 16; k4++) {
        float4 xv = xr[k4];
        const float4* wk = W4 + wbase + k4;
#pragma unroll
        for (int c = 0; c < FH; c++) {
            float4 wv = wk[c * 34];          // ds_read_b128, 2-addr bank-disjoint
            a[c] = fmaf(xv.w, wv.w, fmaf(xv.z, wv.z,
                   fmaf(xv.y, wv.y, fmaf(xv.x, wv.x, a[c]))));
        }
    }
#pragma unroll
    for (int c = 0; c < FH; c++) a[c] += __shfl_xor(a[c], 1);
    if (kh == 0) {
        float dv = dinv[row];
        __half2* hp = (__half2*)(hs1 + ((size_t)row << 6));
#pragma unroll
        for (int c = 0; c < HSTRIDE / 2; c++) {
            float lo = (2 * c     < FH) ? a[2 * c] * dv     : 0.f;
            float hi = (2 * c + 1 < FH) ? a[2 * c + 1] * dv : 0.f;
            hp[c] = __floats2half2_rn(lo, hi);
        }
    }
}

// hs2[row] = fp16((h1[row] @ W2) * dinv[row]). Two threads per row, c-halves
// 0..25 / 26..49 (both compute 26 cols; ch1's top 2 hit zeroed pad rows).
// W2 staged c-major [52][52] floats: half-offset 26*52 = 1352 = 8 mod 32 ->
// the two b128 broadcast addresses are bank-disjoint. Store bases at half
// offsets 0 / 26 are both 4B-aligned for half2. Pad cols 50..63 of regular
// rows stay garbage (only gather lanes >= FH see them; never stored).
#define W2S 13             // c-stride in float4 units (= 52 floats)
__global__ __launch_bounds__(256) void gemm2_kernel(
    const float* __restrict__ h1, const float* __restrict__ W,
    const float* __restrict__ dinv, __half* __restrict__ hs2, int n) {
    __shared__ __align__(16) float Ws[52 * 52];    // 10.8 KB
    int t = threadIdx.x;
    for (int i = t; i < FH * FH; i += 256) {
        int k = i / FH;
        int c = i - k * FH;
        Ws[c * 52 + k] = W[i];                     // transpose to c-major
    }
    for (int i = t; i < 2 * 52; i += 256) Ws[FH * 52 + i] = 0.f;  // pad rows 50,51
    __syncthreads();
    int row = blockIdx.x * 128 + (t >> 1);
    int ch = t & 1;
    if (row >= n) return;   // no cross-lane ops below; divergent exit safe
    const float* xp = h1 + (size_t)row * FH;
    float xr[FH];
#pragma unroll
    for (int k = 0; k < FH; k++) xr[k] = xp[k];
    float a[26];
#pragma unroll
    for (int c = 0; c < 26; c++) a[c] = 0.f;
    const float4* W4 = (const float4*)Ws;
    int cbase = ch * 26;
    for (int k4 = 0; k4 < 12; k4++) {              // k = 0..47
#pragma unroll
        for (int c = 0; c < 26; c++) {
            float4 wv = W4[(cbase + c) * W2S + k4];
            a[c] = fmaf(xr[4 * k4 + 3], wv.w, fmaf(xr[4 * k4 + 2], wv.z,
                   fmaf(xr[4 * k4 + 1], wv.y, fmaf(xr[4 * k4], wv.x, a[c]))));
        }
    }
    const float2* W2v = (const float2*)Ws;
#pragma unroll
    for (int c = 0; c < 26; c++) {                 // k tail = 48,49
        float2 wt = W2v[(cbase + c) * 26 + 24];
        a[c] = fmaf(xr[49], wt.y, fmaf(xr[48], wt.x, a[c]));
    }
    float dv = dinv[row];
    __half2* hp = (__half2*)(hs2 + ((size_t)row << 6) + cbase);
    int nst = ch ? 12 : 13;                        // cols 0..25 / 26..49
    for (int j = 0; j < nst; j++)
        hp[j] = __floats2half2_rn(a[2 * j] * dv, a[2 * j + 1] * dv);
}

// one wave per dst row: acc = hs[self] + sum hs[csr[...]]; x16 branchless
// unroll (lanes >= rem hold sentinel n whose hs row is zero), 16 gather
// loads in flight per vmcnt batch. out = relu?(dinv*acc + b), fp32.
__global__ __launch_bounds__(256) void gather_kernel(
    const __half* __restrict__ hs, const int* __restrict__ rbeg,
    const int* __restrict__ rend, const int* __restrict__ csr,
    const float* __restrict__ dinv, const float* __restrict__ b,
    float* __restrict__ out, int n, int do_relu) {
    int wid = blockIdx.x * 4 + (threadIdx.x >> 6);
    int lane = threadIdx.x & 63;
    if (wid >= n) return;
    int beg = rbeg[wid];
    int end = rend[wid];
    float acc = __half2float(hs[((size_t)wid << 6) + lane]);  // self-loop term
    for (int base = beg; base < end; base += 64) {
        int rem = end - base;
        int idx = (lane < rem) ? csr[base + lane] : n;   // n = zero sentinel
        int cnt = rem < 64 ? rem : 64;
        for (int j = 0; j < cnt; j += 16) {
            float v[16];
#pragma unroll
            for (int u = 0; u < 16; u++) {
                int s = __shfl(idx, j + u);
                v[u] = __half2float(hs[((size_t)s << 6) + lane]);
            }
            float s01 = (v[0] + v[1]) + (v[2] + v[3]);
            float s23 = (v[4] + v[5]) + (v[6] + v[7]);
            float s45 = (v[8] + v[9]) + (v[10] + v[11]);
            float s67 = (v[12] + v[13]) + (v[14] + v[15]);
            acc += (s01 + s23) + (s45 + s67);
        }
    }
    if (lane < FH) {
        float o = fmaf(dinv[wid], acc, b[lane]);
        if (do_relu) o = fmaxf(o, 0.f);
        out[(size_t)wid * FH + lane] = o;
    }
}

extern "C" void kernel_launch(void* const* d_in, const int* in_sizes, int n_in,
                              void* d_out, int out_size, void* d_ws, size_t ws_size,
                              hipStream_t stream) {
    const float* x  = (const float*)d_in[0];
    const float* W1 = (const float*)d_in[1];
    const float* b1 = (const float*)d_in[2];
    const float* W2 = (const float*)d_in[3];
    const float* b2 = (const float*)d_in[4];
    const int*   ei = (const int*)d_in[5];

    int n = in_sizes[0] / FIN;   // 100000
    int E = in_sizes[5] / 2;     // 1600000
    const int* src = ei;
    const int* dst = ei + E;
    int NB = (n + BSIZE - 1) >> BSHIFT;   // 782

    char* ws = (char*)d_ws;
    size_t off = 0;
    auto alloc = [&](size_t bytes) {
        void* p = ws + off;
        off = (off + bytes + 511) & ~(size_t)511;
        return p;
    };
    size_t hs_bytes   = (size_t)(n + 1) * HSTRIDE * 2;
    size_t slab_bytes = (size_t)NB * CAP * 4;
    size_t un_bytes   = slab_bytes > hs_bytes ? slab_bytes : hs_bytes;

    int*          gcursor = (int*)alloc((size_t)MAXNB * 4);
    int*          rbeg    = (int*)alloc((size_t)n * 4);
    int*          rend    = (int*)alloc((size_t)n * 4);
    float*        dinv    = (float*)alloc((size_t)n * 4);
    int*          csr     = (int*)alloc(slab_bytes);
    __half*       hs1     = (__half*)alloc(hs_bytes);
    void*         un      = alloc(un_bytes);          // packed, then hs2
    unsigned int* packed  = (unsigned int*)un;        // dead after bucket_build
    __half*       hs2     = (__half*)un;              // live after gemm1
    float*        out     = (float*)d_out;            // also layer-1 h buffer

    hipMemsetAsync(gcursor, 0, (size_t)MAXNB * 4, stream);

    int pChunks = (E + PCHUNK - 1) / PCHUNK;   // 391
    partition_kernel<<<pChunks, 256, 0, stream>>>(src, dst, gcursor, packed, E, NB);
    bucket_build_kernel<<<NB, 256, 0, stream>>>(packed, gcursor, rbeg, rend, dinv, csr, n);

    int g1Blocks = (n + 127) / 128;       // 2 threads per row (K halves)
    int g2Blocks = (n + 127) / 128;       // 2 threads per row (c halves)
    int gatherBlocks = (n + 3) / 4;       // 4 waves/block, 1 wave/row

    gemm1_kernel<<<g1Blocks, 256, 0, stream>>>(x, W1, dinv, hs1, hs2, n);
    gather_kernel<<<gatherBlocks, 256, 0, stream>>>(hs1, rbeg, rend, csr, dinv, b1, out, n, 1);
    gemm2_kernel<<<g2Blocks, 256, 0, stream>>>(out, W2, dinv, hs2, n);
    gather_kernel<<<gatherBlocks, 256, 0, stream>>>(hs2, rbeg, rend, csr, dinv, b2, out, n, 0);
}